// Round 7
// baseline (331.860 us; speedup 1.0000x reference)
//
#include <hip/hip_runtime.h>

#define E_EDGES 32768
#define NN 8192
#define HID 128

typedef _Float16 half8 __attribute__((ext_vector_type(8)));
typedef float f32x4 __attribute__((ext_vector_type(4)));

// ---- B matrix sizes: per split (TCP+2) chunks of 32k x CO (2 pad chunks for
// clamp-free prefetch), 4 splits. TCP: L0=20, L1=36, L2=68 (content CI chunks
// + b2 tail + zero pad -> uniform, branch-free K-loop).
#define S0 (4 * 22 * 1024)
#define S1 (4 * 38 * 2048)
#define S2 (4 * 70 * 2048)
#define ZTOT (8192 * 32 + 8192 * 64 + 8192 * 64 + 512 * 64 + 512)

// In-chunk half order matches the K-loop's fragment reads:
// m = ((fc*64 + quad*16 + l15)*8 + j), k_local = cl*32 + quad*8 + j,
// n = fc*16 + l15  -> one wave's b-frag read = contiguous 1 KB.
__device__ __forceinline__ void prep_one(int idx, int l2ci, int l2co, int tcp2,
                                         const float* __restrict__ W2,
                                         const float* __restrict__ b2,
                                         _Float16* __restrict__ out) {
  int CI = 1 << l2ci, CO = 1 << l2co;
  int CH = 32 * CO;
  int per_split = tcp2 * CH;
  int y = idx / per_split;
  int r = idx - y * per_split;
  int cl = r / CH;
  int m = r & (CH - 1);
  int j = m & 7, l15 = (m >> 3) & 15, quad = (m >> 7) & 3, fc = m >> 9;
  int kl = cl * 32 + quad * 8 + j;
  int n = fc * 16 + l15;
  int kmain = 32 * CI;
  float v = 0.f;
  if (kl < kmain) {
    int h = y * 32 + (kl >> l2ci), i = kl & (CI - 1);
    v = W2[(h * CI + i) * CO + n];
  } else if (y == 3 && kl < kmain + CI) {
    v = b2[(kl - kmain) * CO + n];
  }
  out[idx] = (_Float16)v;
}

__global__ void prep_k(float* __restrict__ zr,
                       const float* __restrict__ W2a, const float* __restrict__ b2a, _Float16* __restrict__ oa,
                       const float* __restrict__ W2b, const float* __restrict__ b2b, _Float16* __restrict__ ob,
                       const float* __restrict__ W2c, const float* __restrict__ b2c, _Float16* __restrict__ oc) {
  int idx = blockIdx.x * 256 + threadIdx.x;
  if (idx < ZTOT) { zr[idx] = 0.f; return; }
  idx -= ZTOT;
  if (idx < S0) { prep_one(idx, 4, 5, 22, W2a, b2a, oa); return; }
  idx -= S0;
  if (idx < S1) { prep_one(idx, 5, 6, 38, W2b, b2b, ob); return; }
  idx -= S1;
  if (idx < S2) prep_one(idx, 6, 6, 70, W2c, b2c, oc);
}

// ---- main fused kernel: edge MLP1 + Z@W2r GEMM (split-K=4) ----------------
// ONE block per CU (grid 64x4, ~280 VGPR -> 1 wave/SIMD). 4 waves stream the
// SAME B addresses (leader misses L2, followers hit L1), R=8 row-frags per
// B-frag (4x better B-reuse than R6). A-side x gathered directly to registers;
// he in 40KB LDS tile, b128 window reads. Barrier-free, branch-free K-loop
// with depth-2 register prefetch into zero-padded B. Atomic scatter epilogue.
template <int CI, int CO>
__launch_bounds__(256, 1)
__global__ void msg_mfma_k(const float* __restrict__ xcur, const int* __restrict__ src,
                           const int* __restrict__ dst, const float* __restrict__ eattr,
                           const float* __restrict__ W1, const float* __restrict__ b1,
                           const _Float16* __restrict__ Bsw, float* __restrict__ agg) {
  constexpr int ME = 512;
  constexpr int FC = CO / 16;
  constexpr int CH8 = 4 * CO;                  // half8s per 32-k chunk
  constexpr int TCP = (CI == 64) ? 68 : ((CI == 32) ? 36 : 20);
  constexpr int CW = (CI == 64) ? 16 : ((CI == 32) ? 8 : 4);  // chunks / 8-h window
  constexpr int NV = (CI == 64) ? 2 : 1;
  constexpr int HS = 40;

  __shared__ __align__(16) _Float16 he_t[ME * HS];  // [e][h_local 0..31]
  __shared__ float ea_s[ME * 5];
  __shared__ float W1s[5 * 32];
  __shared__ float b1s[32];
  __shared__ int src_s[ME];
  __shared__ int dst_s[ME];

  int t = threadIdx.x;
  int e0 = blockIdx.x * ME;
  int y = blockIdx.y;
  int hbeg = y * 32;

  for (int j = t; j < ME * 5; j += 256) ea_s[j] = eattr[e0 * 5 + j];
  if (t < 160) W1s[t] = W1[(t >> 5) * HID + hbeg + (t & 31)];
  if (t < 32) b1s[t] = b1[hbeg + t];
  src_s[t] = src[e0 + t]; src_s[t + 256] = src[e0 + 256 + t];
  dst_s[t] = dst[e0 + t]; dst_s[t + 256] = dst[e0 + 256 + t];
  __syncthreads();

  // edge MLP1 for this split's 32 h, transposed [e][h]
  for (int j = t; j < 32 * ME; j += 256) {
    int hl = j >> 9, e = j & (ME - 1);
    float v = b1s[hl];
#pragma unroll
    for (int d = 0; d < 5; ++d) v += ea_s[e * 5 + d] * W1s[d * 32 + hl];
    he_t[e * HS + hl] = (_Float16)fmaxf(v, 0.f);
  }
  __syncthreads();                             // last barrier

  int lane = t & 63;
  int w = t >> 6;
  int quad = lane >> 4, l15 = lane & 15;
  int hsel = quad >> 1;                        // CI=16 h-select
  int qoff = quad * 16 + l15;                  // b-frag lane offset (half8 units)

  // A-side x fragments: direct global gather -> registers (one-time)
  half8 xreg[8][NV];
  const float4* xp = (const float4*)xcur;
#pragma unroll
  for (int fr = 0; fr < 8; ++fr) {
    int e = w * 128 + fr * 16 + l15;
    int row = src_s[e];
#pragma unroll
    for (int v = 0; v < NV; ++v) {
      int i0 = (quad * 8 + v * 32) & (CI - 1);
      float4 aa = xp[row * (CI / 4) + i0 / 4];
      float4 bb = xp[row * (CI / 4) + i0 / 4 + 1];
      half8 h = {(_Float16)aa.x, (_Float16)aa.y, (_Float16)aa.z, (_Float16)aa.w,
                 (_Float16)bb.x, (_Float16)bb.y, (_Float16)bb.z, (_Float16)bb.w};
      xreg[fr][v] = h;
    }
  }

  f32x4 acc[8][FC];
#pragma unroll
  for (int fr = 0; fr < 8; ++fr)
#pragma unroll
    for (int fc = 0; fc < FC; ++fc)
#pragma unroll
      for (int r = 0; r < 4; ++r) acc[fr][fc][r] = 0.f;

  const half8* bs8 = (const half8*)Bsw + (size_t)y * (TCP + 2) * CH8;

  half8 breg[2][FC];
#pragma unroll
  for (int p = 0; p < 2; ++p)
#pragma unroll
    for (int fc = 0; fc < FC; ++fc)
      breg[p][fc] = bs8[(size_t)p * CH8 + fc * 64 + qoff];

#pragma unroll 1
  for (int win = 0; win < 4; ++win) {
    half8 hregw[8];
#pragma unroll
    for (int fr = 0; fr < 8; ++fr)
      hregw[fr] = *(const half8*)&he_t[(w * 128 + fr * 16 + l15) * HS + win * 8];
    const half8* bw8 = bs8 + (size_t)win * CW * CH8;
#pragma unroll
    for (int cc = 0; cc < CW; ++cc) {
      int p = cc & 1;
      int vi = (CI == 64) ? (cc & 1) : 0;
      half8 a[8];
#pragma unroll
      for (int fr = 0; fr < 8; ++fr) {
        _Float16 hv;
        if (CI == 64)      hv = hregw[fr][cc >> 1];
        else if (CI == 32) hv = hregw[fr][cc];
        else               hv = hregw[fr][cc * 2 + hsel];
        half8 hb = {hv, hv, hv, hv, hv, hv, hv, hv};
        a[fr] = xreg[fr][vi] * hb;
      }
#pragma unroll
      for (int fc = 0; fc < FC; ++fc)
#pragma unroll
        for (int fr = 0; fr < 8; ++fr)
          acc[fr][fc] = __builtin_amdgcn_mfma_f32_16x16x32_f16(a[fr], breg[p][fc], acc[fr][fc], 0, 0, 0);
#pragma unroll
      for (int fc = 0; fc < FC; ++fc)
        breg[p][fc] = bw8[(size_t)(cc + 2) * CH8 + fc * 64 + qoff];
    }
  }

  // tail chunks (b2 rows pair with x, he==1; pad rows are zero B)
  const half8* bt8 = bs8 + (size_t)CI * CH8;
#pragma unroll
  for (int j = 0; j < TCP - CI; ++j) {
    int p = j & 1;                             // CI even
    int vi = (CI == 64) ? (j & 1) : 0;
#pragma unroll
    for (int fc = 0; fc < FC; ++fc)
#pragma unroll
      for (int fr = 0; fr < 8; ++fr)
        acc[fr][fc] = __builtin_amdgcn_mfma_f32_16x16x32_f16(xreg[fr][vi], breg[p][fc], acc[fr][fc], 0, 0, 0);
#pragma unroll
    for (int fc = 0; fc < FC; ++fc)
      breg[p][fc] = bt8[(size_t)(j + 2) * CH8 + fc * 64 + qoff];
  }

  // epilogue: scatter into agg via device atomics. C/D: row=quad*4+r, col=l15.
#pragma unroll
  for (int fr = 0; fr < 8; ++fr)
#pragma unroll
    for (int r = 0; r < 4; ++r) {
      int el = w * 128 + fr * 16 + quad * 4 + r;
      int d = dst_s[el];
      float* base = agg + (size_t)d * CO + l15;
#pragma unroll
      for (int fc = 0; fc < FC; ++fc)
        atomicAdd(base + fc * 16, acc[fr][fc][r]);
    }
}

// ------- finish: ELU(agg + x@root + bias); fin1 counts, fin3 pools ---------
template <int CI, int CO, bool POOL, bool CNT>
__global__ void fin_k(const float* __restrict__ xcur, const float* __restrict__ root,
                      const float* __restrict__ bias, const float* __restrict__ agg,
                      const int* __restrict__ n2s, int* __restrict__ cnt_sub,
                      float* __restrict__ ssum, float* __restrict__ xnext) {
  constexpr int NB = 256 / CO;
  __shared__ float xs[NB * CI];
  int t = threadIdx.x;
  int n0 = blockIdx.x * NB;
  for (int j = t; j < NB * CI; j += 256) xs[j] = xcur[n0 * CI + j];
  __syncthreads();
  int nl = t / CO, o = t & (CO - 1);
  int n = n0 + nl;
  float a = bias[o] + agg[n * CO + o];
#pragma unroll
  for (int i = 0; i < CI; ++i) a += xs[nl * CI + i] * root[i * CO + o];
  float r = a > 0.f ? a : expm1f(a);
  if (CNT && o == 0) atomicAdd(&cnt_sub[n2s[n]], 1);
  if (POOL) atomicAdd(&ssum[(n2s[n] << 6) + o], r);
  else xnext[n * CO + o] = r;
}

// ------- head: per-graph pool (32 blocks x 64 thr) + MLP -------------------
__device__ __forceinline__ int lbound(const int* __restrict__ a, int n, int v) {
  int lo = 0, hi = n;
  while (lo < hi) { int m = (lo + hi) >> 1; if (a[m] < v) lo = m + 1; else hi = m; }
  return lo;
}

__global__ void head_k(const float* __restrict__ ssum, const int* __restrict__ cnt_sub,
                       const int* __restrict__ s2g,
                       const float* __restrict__ w1, const float* __restrict__ b1,
                       const float* __restrict__ w2, const float* __restrict__ b2,
                       const float* __restrict__ w3, const float* __restrict__ b3,
                       float* __restrict__ out) {
  int g = blockIdx.x;
  int t = threadIdx.x;  // 64 threads
  __shared__ float m[64], s1[32], s2[16];
  int slo = lbound(s2g, 512, g);
  int shi = lbound(s2g, 512, g + 1);
  float acc = 0.f;
  for (int s = slo; s < shi; ++s)
    acc += ssum[(s << 6) + t] / fmaxf((float)cnt_sub[s], 1.f);
  m[t] = acc / fmaxf((float)(shi - slo), 1.f);
  __syncthreads();
  if (t < 32) {
    float a = b1[t];
    for (int i = 0; i < 64; ++i) a += m[i] * w1[i * 32 + t];
    s1[t] = a > 0.f ? a : expm1f(a);
  }
  __syncthreads();
  if (t < 16) {
    float a = b2[t];
    for (int i = 0; i < 32; ++i) a += s1[i] * w2[i * 16 + t];
    s2[t] = a > 0.f ? a : expm1f(a);
  }
  __syncthreads();
  if (t == 0) {
    float a = b3[0];
    for (int i = 0; i < 16; ++i) a += s2[i] * w3[i];
    out[g] = a;
  }
}

extern "C" void kernel_launch(void* const* d_in, const int* in_sizes, int n_in,
                              void* d_out, int out_size, void* d_ws, size_t ws_size,
                              hipStream_t stream) {
  (void)in_sizes; (void)n_in; (void)out_size; (void)ws_size;
  const float* x0 = (const float*)d_in[0];
  const int* ei = (const int*)d_in[1];
  const float* ea = (const float*)d_in[2];
  const int* n2s = (const int*)d_in[3];
  const int* s2g = (const int*)d_in[4];
  const float* W1_[3] = {(const float*)d_in[5], (const float*)d_in[11], (const float*)d_in[17]};
  const float* b1_[3] = {(const float*)d_in[6], (const float*)d_in[12], (const float*)d_in[18]};
  const float* W2_[3] = {(const float*)d_in[7], (const float*)d_in[13], (const float*)d_in[19]};
  const float* b2_[3] = {(const float*)d_in[8], (const float*)d_in[14], (const float*)d_in[20]};
  const float* rt_[3] = {(const float*)d_in[9], (const float*)d_in[15], (const float*)d_in[21]};
  const float* bs_[3] = {(const float*)d_in[10], (const float*)d_in[16], (const float*)d_in[22]};
  const float* fc1w = (const float*)d_in[23]; const float* fc1b = (const float*)d_in[24];
  const float* fc2w = (const float*)d_in[25]; const float* fc2b = (const float*)d_in[26];
  const float* fc3w = (const float*)d_in[27]; const float* fc3b = (const float*)d_in[28];
  float* out = (float*)d_out;

  const int* srcp = ei;
  const int* dstp = ei + E_EDGES;

  char* wsb = (char*)d_ws;
  size_t off = 0;
  auto alloc = [&](size_t bytes) {
    void* p = wsb + off;
    off += (bytes + 255) & ~(size_t)255;
    return p;
  };
  _Float16* Bsw0 = (_Float16*)alloc((size_t)S0 * 2);
  _Float16* Bsw1 = (_Float16*)alloc((size_t)S1 * 2);
  _Float16* Bsw2 = (_Float16*)alloc((size_t)S2 * 2);
  // zero region (contiguous, all sizes multiples of 256B)
  float* agg1 = (float*)alloc((size_t)NN * 32 * 4);
  float* agg2 = (float*)alloc((size_t)NN * 64 * 4);
  float* agg3 = (float*)alloc((size_t)NN * 64 * 4);
  float* ssum = (float*)alloc((size_t)512 * 64 * 4);
  int* cnt_sub = (int*)alloc((size_t)512 * 4);
  float* x1 = (float*)alloc((size_t)NN * 32 * 4);
  float* x2 = (float*)alloc((size_t)NN * 64 * 4);

  const int preptot = ZTOT + S0 + S1 + S2;
  prep_k<<<(preptot + 255) / 256, 256, 0, stream>>>(agg1, W2_[0], b2_[0], Bsw0,
                                                    W2_[1], b2_[1], Bsw1,
                                                    W2_[2], b2_[2], Bsw2);

  dim3 mg(E_EDGES / 512, 4);
  msg_mfma_k<16, 32><<<mg, 256, 0, stream>>>(x0, srcp, dstp, ea, W1_[0], b1_[0], Bsw0, agg1);
  fin_k<16, 32, false, true><<<NN / 8, 256, 0, stream>>>(x0, rt_[0], bs_[0], agg1, n2s, cnt_sub, ssum, x1);
  msg_mfma_k<32, 64><<<mg, 256, 0, stream>>>(x1, srcp, dstp, ea, W1_[1], b1_[1], Bsw1, agg2);
  fin_k<32, 64, false, false><<<NN / 4, 256, 0, stream>>>(x1, rt_[1], bs_[1], agg2, n2s, cnt_sub, ssum, x2);
  msg_mfma_k<64, 64><<<mg, 256, 0, stream>>>(x2, srcp, dstp, ea, W1_[2], b1_[2], Bsw2, agg3);
  fin_k<64, 64, true, false><<<NN / 4, 256, 0, stream>>>(x2, rt_[2], bs_[2], agg3, n2s, cnt_sub, ssum, nullptr);

  head_k<<<32, 64, 0, stream>>>(ssum, cnt_sub, s2g, fc1w, fc1b, fc2w, fc2b, fc3w, fc3b, out);
}